// Round 1
// 426.703 us; speedup vs baseline: 1.0244x; 1.0244x over previous
//
#include <hip/hip_runtime.h>
#include <cstdint>
#include <cstddef>

// GAT layer, N=8192, Fin=128, Fout=64.
// h = elu( softmax_j(mask(leaky_relu(Wh1_i + Wh2_j))) @ Wh )
// R5: phaseB rebuilt as an explicit depth-2 software pipeline.
//  - vmcnt is IN-ORDER: any wait on an L2 load drains every HBM load issued
//    before it. R4 issued adj prefetch FIRST each block -> every block's
//    af/MFMA waits drained the prefetch queue -> latency-serialized.
//  - Now: per body, L2 loads (Wh2/Whbt for block e+1) issue BEFORE the HBM
//    adj reload (block e+2). Waits only ever drain L2 loads; adj always has
//    ~2 bodies of slack (4 KB in flight per wave, 64 KB/CU).
//  - Denominator via 5th MFMA with bf16-ones B operand (sums the exact same
//    truncated-bf16 P values as the numerator; kills 16 VALU adds/body).

#define NN   8192
#define FIN  128
#define FOUT 64
#define SJ   8                 // j-split per row-tile: 512*SJ = 4096 wave-tasks
#define JCHUNK (NN / SJ)       // 1024 columns per wave

typedef __attribute__((ext_vector_type(8))) short   short8;   // 8 bf16 (4 VGPRs)
typedef __attribute__((ext_vector_type(4))) float   f32x4;

#define LOG2E 1.44269504088896340736f

// ---------------------------------------------------------------- Phase A ---
// One wave per 4 rows: Wh[row][f] (f = lane), store bf16 transposed
// Whbt[f][row], wave-reduce Wh1 = Wh.a1, Wh2 = Wh.a2 (pre-scaled by log2e so
// phaseB uses exp2 directly; leaky_relu commutes with positive scaling).
__global__ __launch_bounds__(256) void gat_phaseA(
    const float* __restrict__ x, const float* __restrict__ W,
    const float* __restrict__ a, unsigned short* __restrict__ Whbt,
    float* __restrict__ Wh1, float* __restrict__ Wh2)
{
  const int wid  = threadIdx.x >> 6;
  const int lane = threadIdx.x & 63;
  const int row0 = (blockIdx.x * 4 + wid) * 4;
  const float a1 = a[lane];
  const float a2 = a[FOUT + lane];
  float acc[4] = {0.f, 0.f, 0.f, 0.f};
#pragma unroll 4
  for (int k = 0; k < FIN; k += 4) {
    float4 wv0 = make_float4(W[(k+0)*FOUT + lane], W[(k+1)*FOUT + lane],
                             W[(k+2)*FOUT + lane], W[(k+3)*FOUT + lane]);
#pragma unroll
    for (int r = 0; r < 4; ++r) {
      float4 xv = *(const float4*)(x + (row0 + r) * FIN + k);
      acc[r] = fmaf(xv.x, wv0.x, acc[r]);
      acc[r] = fmaf(xv.y, wv0.y, acc[r]);
      acc[r] = fmaf(xv.z, wv0.z, acc[r]);
      acc[r] = fmaf(xv.w, wv0.w, acc[r]);
    }
  }
#pragma unroll
  for (int r = 0; r < 4; ++r) {
    // bf16 round-to-nearest-even
    unsigned int u = __float_as_uint(acc[r]);
    unsigned int rb = (u + 0x7FFFu + ((u >> 16) & 1u)) >> 16;
    Whbt[lane * NN + row0 + r] = (unsigned short)rb;
    float s1 = acc[r] * a1, s2 = acc[r] * a2;
#pragma unroll
    for (int off = 32; off; off >>= 1) {
      s1 += __shfl_xor(s1, off);
      s2 += __shfl_xor(s2, off);
    }
    if (lane == 0) { Wh1[row0 + r] = s1 * LOG2E; Wh2[row0 + r] = s2 * LOG2E; }
  }
}

// ---------------------------------------------------------------- Phase B ---
// Wave task = (rowTile of 16 rows) x (j-chunk of 1024). A-frag (P) in
// registers: lane holds rows m=lane&15, k=(lane>>4)*8+e. 32 column-blocks of
// 32, manually unrolled x2 for static ping-pong register rotation:
//   adj (HBM, nontemporal): distance 2, slots adA/adB
//   Wh2 + Whbt B-frags (L2-hot): distance 1, slots w2A/w2B, bA*/bB*
// Per body, issue order: [L2 next-block] -> compute af -> [HBM block+2] ->
// 5x MFMA. Waits never drain the adj queue.
#define GAT_BODY(AD0, AD1, W2C0, W2C1, BC0, BC1, BC2, BC3,                    \
                 W2N0, W2N1, BN0, BN1, BN2, BN3, JN1, JN2)                    \
  {                                                                           \
    W2N0 = *(const f32x4*)(w2base + (JN1));                                   \
    W2N1 = *(const f32x4*)(w2base + (JN1) + 4);                               \
    BN0  = *(const short8*)(bbase + (JN1));                                   \
    BN1  = *(const short8*)(bbase + (JN1) + 16 * NN);                         \
    BN2  = *(const short8*)(bbase + (JN1) + 32 * NN);                         \
    BN3  = *(const short8*)(bbase + (JN1) + 48 * NN);                         \
    short8 af;                                                                \
    _Pragma("unroll")                                                         \
    for (int e = 0; e < 4; ++e) {                                             \
      float t0 = wh1 + (W2C0)[e];                                             \
      t0 = fmaxf(t0, 0.2f * t0);              /* leaky_relu, scale-inv */     \
      float p0 = exp2f(t0) * (AD0)[e];        /* mask: adj is 0.0/1.0 */      \
      af[e] = (short)(__float_as_uint(p0) >> 16);   /* trunc to bf16 */       \
      float t1 = wh1 + (W2C1)[e];                                             \
      t1 = fmaxf(t1, 0.2f * t1);                                              \
      float p1 = exp2f(t1) * (AD1)[e];                                        \
      af[4 + e] = (short)(__float_as_uint(p1) >> 16);                         \
    }                                                                         \
    AD0 = __builtin_nontemporal_load((const f32x4*)(adjrow + (JN2)));         \
    AD1 = __builtin_nontemporal_load((const f32x4*)(adjrow + (JN2) + 4));     \
    c0 = __builtin_amdgcn_mfma_f32_16x16x32_bf16(af, BC0,  c0, 0, 0, 0);      \
    c1 = __builtin_amdgcn_mfma_f32_16x16x32_bf16(af, BC1,  c1, 0, 0, 0);      \
    c2 = __builtin_amdgcn_mfma_f32_16x16x32_bf16(af, BC2,  c2, 0, 0, 0);      \
    c3 = __builtin_amdgcn_mfma_f32_16x16x32_bf16(af, BC3,  c3, 0, 0, 0);      \
    c4 = __builtin_amdgcn_mfma_f32_16x16x32_bf16(af, ones, c4, 0, 0, 0);      \
  }

__global__ __launch_bounds__(256, 4) void gat_phaseB(
    const float* __restrict__ adj, const unsigned short* __restrict__ Whbt,
    const float* __restrict__ Wh1, const float* __restrict__ Wh2,
    float* __restrict__ accbuf, float* __restrict__ denbuf, int nslices)
{
  const int wid  = threadIdx.x >> 6;
  const int lane = threadIdx.x & 63;
  const int task = blockIdx.x * 4 + wid;
  const int rowTile = task / SJ;
  const int jc      = task % SJ;
  const int m = lane & 15;
  const int q = lane >> 4;
  const int row = rowTile * 16 + m;
  const float wh1 = Wh1[row];
  // per-lane bases with the q*8 element offset folded in
  const float* adjrow          = adj  + (size_t)row * NN + q * 8;
  const unsigned short* bbase  = Whbt + m * NN + q * 8;
  const float* w2base          = Wh2  + q * 8;

  f32x4 c0 = {0.f,0.f,0.f,0.f}, c1 = c0, c2 = c0, c3 = c0, c4 = c0;
  short8 ones;                       // bf16 1.0 column for the denominator
#pragma unroll
  for (int e = 0; e < 8; ++e) ones[e] = (short)0x3F80;

  const int jbeg = jc * JCHUNK;

  // pipeline registers
  f32x4 adA0, adA1, adB0, adB1;      // adj, distance 2
  f32x4 w2A0, w2A1, w2B0, w2B1;      // Wh2, distance 1
  short8 bA0, bA1, bA2, bA3, bB0, bB1, bB2, bB3;   // Whbt B-frags, distance 1

  // ---- prologue: L2 loads for block 0 FIRST, then HBM adj for blocks 0,1
  w2A0 = *(const f32x4*)(w2base + jbeg);
  w2A1 = *(const f32x4*)(w2base + jbeg + 4);
  bA0  = *(const short8*)(bbase + jbeg);
  bA1  = *(const short8*)(bbase + jbeg + 16 * NN);
  bA2  = *(const short8*)(bbase + jbeg + 32 * NN);
  bA3  = *(const short8*)(bbase + jbeg + 48 * NN);
  adA0 = __builtin_nontemporal_load((const f32x4*)(adjrow + jbeg));
  adA1 = __builtin_nontemporal_load((const f32x4*)(adjrow + jbeg + 4));
  adB0 = __builtin_nontemporal_load((const f32x4*)(adjrow + jbeg + 32));
  adB1 = __builtin_nontemporal_load((const f32x4*)(adjrow + jbeg + 36));

  // 32 blocks of 32 columns; unrolled x2 -> 16 static double-bodies so every
  // block offset folds into a compile-time load offset. Tail prefetches wrap
  // to jbeg (valid addresses, values unused).
#pragma unroll
  for (int bb = 0; bb < 32; bb += 2) {
    const int jE = bb * 32;
    const int j1 = (bb + 1 < 32) ? jE + 32 : 0;   // block e+1
    const int j2 = (bb + 2 < 32) ? jE + 64 : 0;   // block e+2
    const int j3 = (bb + 3 < 32) ? jE + 96 : 0;   // block e+3
    GAT_BODY(adA0, adA1, w2A0, w2A1, bA0, bA1, bA2, bA3,
             w2B0, w2B1, bB0, bB1, bB2, bB3, jbeg + j1, jbeg + j2);
    GAT_BODY(adB0, adB1, w2B0, w2B1, bB0, bB1, bB2, bB3,
             w2A0, w2A1, bA0, bA1, bA2, bA3, jbeg + j2, jbeg + j3);
  }

  // c4 layout (C/D map): lane (m,q), reg r holds rowsum of row q*4+r,
  // replicated across the 16 m-lanes -> m==0 lanes publish.
  const int slice = (nslices > 1) ? jc : 0;
  float* accout = accbuf + (size_t)slice * (NN * FOUT);
  float* denout = denbuf + slice * NN;
  f32x4 cc[4] = {c0, c1, c2, c3};
  if (nslices > 1) {            // roomy ws: plain per-slice stores
    if (m == 0) {
#pragma unroll
      for (int r = 0; r < 4; ++r)
        denout[rowTile * 16 + q * 4 + r] = c4[r];
    }
#pragma unroll
    for (int ft = 0; ft < 4; ++ft)
#pragma unroll
      for (int r = 0; r < 4; ++r)
        accout[(rowTile * 16 + q * 4 + r) * FOUT + ft * 16 + m] = cc[ft][r];
  } else {                      // tight ws: atomic accumulate (zeroed first)
    if (m == 0) {
#pragma unroll
      for (int r = 0; r < 4; ++r)
        atomicAdd(&denout[rowTile * 16 + q * 4 + r], c4[r]);
    }
#pragma unroll
    for (int ft = 0; ft < 4; ++ft)
#pragma unroll
      for (int r = 0; r < 4; ++r)
        atomicAdd(&accout[(rowTile * 16 + q * 4 + r) * FOUT + ft * 16 + m], cc[ft][r]);
  }
}

// ---------------------------------------------------------------- Phase C ---
// elu(acc/den), vectorized f32x4 per thread.
__global__ __launch_bounds__(256) void gat_phaseC(
    const float* __restrict__ accbuf, const float* __restrict__ denbuf,
    float* __restrict__ out, int nslices)
{
  const int idx4 = blockIdx.x * 256 + threadIdx.x;   // f32x4 index
  const int idx  = idx4 * 4;
  const int row  = idx >> 6;    // FOUT = 64; 4 elems stay within one row
  f32x4 s = {0.f, 0.f, 0.f, 0.f};
  float d = 0.f;
  for (int sl = 0; sl < nslices; ++sl) {
    f32x4 v = *(const f32x4*)(accbuf + (size_t)sl * (NN * FOUT) + idx);
    s += v;
    d += denbuf[sl * NN + row];
  }
  float inv = 1.0f / d;
  f32x4 o;
#pragma unroll
  for (int e = 0; e < 4; ++e) {
    float v = s[e] * inv;
    o[e] = (v > 0.f) ? v : expm1f(v);   // elu, alpha=1
  }
  *(f32x4*)(out + idx) = o;
}

// ------------------------------------------------------------------ launch --
extern "C" void kernel_launch(void* const* d_in, const int* in_sizes, int n_in,
                              void* d_out, int out_size, void* d_ws, size_t ws_size,
                              hipStream_t stream)
{
  const float* x   = (const float*)d_in[0];   // [8192,128]
  const float* adj = (const float*)d_in[1];   // [8192,8192]
  const float* W   = (const float*)d_in[2];   // [128,64]
  const float* a   = (const float*)d_in[3];   // [128,1]
  float* out = (float*)d_out;                 // [8192,64] fp32

  const size_t accEl = (size_t)NN * FOUT;
  const size_t roomyBytes = (size_t)SJ * accEl * 4 + (size_t)SJ * NN * 4
                          + (size_t)NN * 8 + (size_t)FOUT * NN * 2;
  const int nslices = (ws_size >= roomyBytes) ? SJ : 1;

  char* ws = (char*)d_ws;
  float* accbuf = (float*)ws;
  size_t off = (size_t)nslices * accEl * 4;
  float* denbuf = (float*)(ws + off); off += (size_t)nslices * NN * 4;
  float* Wh1 = (float*)(ws + off);    off += (size_t)NN * 4;
  float* Wh2 = (float*)(ws + off);    off += (size_t)NN * 4;
  unsigned short* Whbt = (unsigned short*)(ws + off);

  if (nslices == 1)   // atomic path needs zeroed acc+den (contiguous)
    hipMemsetAsync(accbuf, 0, accEl * 4 + (size_t)NN * 4, stream);

  gat_phaseA<<<NN / 16, 256, 0, stream>>>(x, W, a, Whbt, Wh1, Wh2);
  gat_phaseB<<<(512 * SJ) / 4, 256, 0, stream>>>(adj, Whbt, Wh1, Wh2,
                                                 accbuf, denbuf, nslices);
  gat_phaseC<<<(NN * FOUT) / 4 / 256, 256, 0, stream>>>(accbuf, denbuf, out, nslices);
}